// Round 18
// baseline (112.882 us; speedup 1.0000x reference)
//
#include <hip/hip_runtime.h>
#include <stdint.h>
#include <stddef.h>

typedef __attribute__((ext_vector_type(8))) short bf16x8;
typedef __attribute__((ext_vector_type(4))) float f32x4;
typedef __attribute__((ext_vector_type(4))) int i32x4;

#define NH 128
#define NW 128
#define NC 64
#define NF 256
#define SLOT 16384                 // one x-row tile in LDS: [w=128][cb=8 x 16B], XOR-swizzled

__device__ __forceinline__ unsigned short f2b(float f) {
  union { float f; uint32_t u; } t; t.f = f;
  uint32_t u = t.u;
  return (unsigned short)((u + 0x7fffu + ((u >> 16) & 1u)) >> 16);
}

// prep: B table only (72 blocks, ~3 us). Per-wave fragment order (R8-verified):
//   u16 elem ((fi*9+s)*16 + cf*2 + kk)*512 + lane*8 + e
//     = kern[(s*64 + (kk*4+(lane>>4))*8 + e)*NF + fi*128 + cf*16 + (lane&15)]
__global__ void prep_bt(const float* __restrict__ kr, unsigned short* __restrict__ ws) {
  int t = blockIdx.x * 256 + threadIdx.x;   // [0, 18432)
  int lane = t & 63;
  int kk   = (t >> 6) & 1;
  int cf   = (t >> 7) & 7;
  int rest = t >> 10;          // fi*9 + s
  int s  = rest % 9;
  int fi = rest / 9;
  int l15 = lane & 15, l4 = lane >> 4;
  int col = fi * 128 + cf * 16 + l15;
  int k0  = s * 64 + (kk * 4 + l4) * 8;
  unsigned short* dst = ws + (size_t)t * 8;
  const float* src = kr + (size_t)k0 * NF + col;
  #pragma unroll
  for (int e = 0; e < 8; ++e) dst[e] = f2b(src[(size_t)e * NF]);
}

// conv: R17 structure (256 thr, 4 waves, 64wx64F wave tile, 3 blocks/CU,
// dbuf B, setprio, in-kernel cast) with SWAPPED MFMA OPERANDS:
// mfma(breg, af) -> D[row=F][col=w], so each lane's 4 acc regs are 4
// CONSECUTIVE F values = one f32x4 in the [w][F] output. Epilogue becomes
// direct NT f32x4 stores (64B/row per instr, HBM sector granularity) —
// the entire LDS-transpose epilogue (64 ds_writes/lane + readback + 3
// barriers) is deleted. A/B operand lane-mappings are identical
// ({row|col}=lane&15, k=(lane>>4)*8+e) so fragments are interchangeable.
__global__ __launch_bounds__(256, 3)
void conv_main(const float* __restrict__ x, const unsigned short* __restrict__ bt,
               const float* __restrict__ bias, float* __restrict__ out)
{
  __shared__ __align__(16) char lds[3 * SLOT];   // 48 KB (A staging only)

  const int tid  = threadIdx.x;
  const int lane = tid & 63;
  const int l15  = lane & 15;
  const int l4   = lane >> 4;
  const int wid  = tid >> 6;
  const int wm   = wid >> 1;    // 2: w-half
  const int wn   = wid & 1;     // 2: F-half of this fi half (64 cols)

  // XCD-aware bijective swizzle: nwg=4096, 512 per XCD.
  int bid  = (int)blockIdx.x;
  int work = (bid & 7) * 512 + (bid >> 3);
  int mi = work >> 1;           // (b,h) flat
  int fi = work & 1;
  int bb = mi >> 7;
  int hh = mi & 127;
  int F0 = fi * 128;

  const char* bimg = (const char*)bt + (size_t)fi * 9 * 16384;
  const int boff = (wn * 4) * 2048 + lane * 16;

  bf16x8 breg[2][4][2];   // double buffer = 64 VGPR, all-static indices

  // ---- prologue: B(0) -> buf0 (issues first, flies under staging VALU) ----
  #pragma unroll
  for (int n = 0; n < 4; ++n)
    #pragma unroll
    for (int kk = 0; kk < 2; ++kk)
      breg[0][n][kk] = *(const bf16x8*)(bimg + boff + n * 2048 + kk * 1024);

  // ---- stage A rows h-1,h,h+1 -> slots 0..2 (cast in-kernel) ----
  #pragma unroll
  for (int i = 0; i < 12; ++i) {
    int idx = tid + i * 256;            // 3072 16B-blocks (3 rows)
    int cb = idx & 7;
    int w  = (idx >> 3) & 127;
    int r  = idx >> 10;                 // 0..2
    int xr = (hh + r + 127) & 127;
    const float* src = x + (((size_t)(bb * NH + xr) * NW + w) * NC + cb * 8);
    float4 a0 = *(const float4*)(src);
    float4 a1 = *(const float4*)(src + 4);
    union { unsigned short u[8]; i32x4 v; } p;
    p.u[0] = f2b(a0.x); p.u[1] = f2b(a0.y); p.u[2] = f2b(a0.z); p.u[3] = f2b(a0.w);
    p.u[4] = f2b(a1.x); p.u[5] = f2b(a1.y); p.u[6] = f2b(a1.z); p.u[7] = f2b(a1.w);
    *(i32x4*)(lds + (r * SLOT + w * 128 + ((cb ^ (w & 7)) << 4))) = p.v;
  }
  __syncthreads();    // A staged; read-only hereafter

  // compressed A-address LUT (R10-verified):
  //   addr(m,dwi) = slotb + ((trow[dwi] + m*2048) & 16383) + swz[dwi]
  //   kk=1 address = kk=0 address XOR 64
  int trow[3], swz[3];
  #pragma unroll
  for (int dwi = 0; dwi < 3; ++dwi) {
    int t = l15 + 1 - dwi;
    trow[dwi] = ((wm * 64 + t) & 127) * 128;
    swz[dwi]  = (l4 ^ (t & 7)) << 4;
  }

  f32x4 acc[4][4];   // [m][n]: D[F-quad rows][w col] per swapped layout
  #pragma unroll
  for (int m = 0; m < 4; ++m)
    #pragma unroll
    for (int n = 0; n < 4; ++n)
      acc[m][n] = (f32x4){0.f, 0.f, 0.f, 0.f};

  #pragma unroll
  for (int s = 0; s < 9; ++s) {
    if (s < 8) {  // depth-1 B prefetch -> other buffer (plain cached loads)
      const char* bs = bimg + (size_t)(s + 1) * 16384 + boff;
      #pragma unroll
      for (int n = 0; n < 4; ++n)
        #pragma unroll
        for (int kk = 0; kk < 2; ++kk)
          breg[(s + 1) & 1][n][kk] = *(const bf16x8*)(bs + n * 2048 + kk * 1024);
    }
    const int dwi   = s / 3;                  // static
    const int slotb = (2 - (s % 3)) * SLOT;   // static
    #pragma unroll
    for (int kk = 0; kk < 2; ++kk) {
      bf16x8 af[4];
      #pragma unroll
      for (int m = 0; m < 4; ++m) {
        int addr = slotb + ((trow[dwi] + m * 2048) & 16383) + swz[dwi];
        af[m] = *(const bf16x8*)(lds + (addr ^ (kk << 6)));
      }
      __builtin_amdgcn_s_setprio(1);
      #pragma unroll
      for (int m = 0; m < 4; ++m)
        #pragma unroll
        for (int n = 0; n < 4; ++n)
          acc[m][n] = __builtin_amdgcn_mfma_f32_16x16x32_bf16(
              breg[s & 1][n][kk], af[m], acc[m][n], 0, 0, 0);   // SWAPPED
      __builtin_amdgcn_s_setprio(0);
    }
  }

  // ---- epilogue: direct NT f32x4 stores (no LDS, no barriers) ----
  // lane (m,n): w = wm*64+m*16+l15, f = F0+wn*64+n*16+l4*4 .. +4
  const size_t rowbase = (size_t)mi * 128;
  #pragma unroll
  for (int n = 0; n < 4; ++n) {
    const int fq = F0 + wn * 64 + n * 16 + l4 * 4;
    f32x4 bq = *(const f32x4*)(bias + fq);
    #pragma unroll
    for (int m = 0; m < 4; ++m) {
      int w = wm * 64 + m * 16 + l15;
      f32x4 v = acc[m][n] + bq;
      __builtin_nontemporal_store(v, (f32x4*)(out + (rowbase + w) * NF + fq));
    }
  }
}

extern "C" void kernel_launch(void* const* d_in, const int* in_sizes, int n_in,
                              void* d_out, int out_size, void* d_ws, size_t ws_size,
                              hipStream_t stream) {
  const float* x    = (const float*)d_in[0];
  const float* kern = (const float*)d_in[1];
  const float* bias = (const float*)d_in[2];
  float* out = (float*)d_out;
  unsigned short* bt = (unsigned short*)d_ws;   // 294912 bytes

  prep_bt<<<dim3(72), dim3(256), 0, stream>>>(kern, bt);
  conv_main<<<dim3(4096), dim3(256), 0, stream>>>(x, bt, bias, out);
}

// Round 19
// 95.150 us; speedup vs baseline: 1.1864x; 1.1864x over previous
//
#include <hip/hip_runtime.h>
#include <stdint.h>
#include <stddef.h>

typedef __attribute__((ext_vector_type(8))) short bf16x8;
typedef __attribute__((ext_vector_type(4))) float f32x4;
typedef __attribute__((ext_vector_type(4))) int i32x4;

#define NH 128
#define NW 128
#define NC 64
#define NF 256
#define SLOT 16384                 // one x-row tile in LDS: [w=128][cb=8 x 16B], XOR-swizzled
#define EBS 136                    // epi row stride (floats): 544B = 34x16, aligned + uniform banks

__device__ __forceinline__ unsigned short f2b(float f) {
  union { float f; uint32_t u; } t; t.f = f;
  uint32_t u = t.u;
  return (unsigned short)((u + 0x7fffu + ((u >> 16) & 1u)) >> 16);
}

// prep: B table only (72 blocks, ~3 us). Per-wave fragment order (R8-verified):
//   u16 elem ((fi*9+s)*16 + cf*2 + kk)*512 + lane*8 + e
//     = kern[(s*64 + (kk*4+(lane>>4))*8 + e)*NF + fi*128 + cf*16 + (lane&15)]
__global__ void prep_bt(const float* __restrict__ kr, unsigned short* __restrict__ ws) {
  int t = blockIdx.x * 256 + threadIdx.x;   // [0, 18432)
  int lane = t & 63;
  int kk   = (t >> 6) & 1;
  int cf   = (t >> 7) & 7;
  int rest = t >> 10;          // fi*9 + s
  int s  = rest % 9;
  int fi = rest / 9;
  int l15 = lane & 15, l4 = lane >> 4;
  int col = fi * 128 + cf * 16 + l15;
  int k0  = s * 64 + (kk * 4 + l4) * 8;
  unsigned short* dst = ws + (size_t)t * 8;
  const float* src = kr + (size_t)k0 * NF + col;
  #pragma unroll
  for (int e = 0; e < 8; ++e) dst[e] = f2b(src[(size_t)e * NF]);
}

// conv: R17 structure (256 thr, 4 waves, 64wx64F wave tile, 3 blocks/CU,
// dbuf B, setprio, in-kernel cast, FULL-LINE NT stores) + R18's swapped
// MFMA operands: mfma(breg, af) puts 4 CONSECUTIVE F values in each lane's
// acc f32x4, so the epilogue LDS deposit is one ds_write_b128 per (m,n)
// (16 instead of 64 LDS write instructions per lane), bias fused as f32x4.
__global__ __launch_bounds__(256, 3)
void conv_main(const float* __restrict__ x, const unsigned short* __restrict__ bt,
               const float* __restrict__ bias, float* __restrict__ out)
{
  __shared__ __align__(16) char lds[3 * SLOT];   // 48 KB (A staging; epi reuses)

  const int tid  = threadIdx.x;
  const int lane = tid & 63;
  const int l15  = lane & 15;
  const int l4   = lane >> 4;
  const int wid  = tid >> 6;
  const int wm   = wid >> 1;    // 2: w-half
  const int wn   = wid & 1;     // 2: F-half of this fi half (64 cols)

  // XCD-aware bijective swizzle: nwg=4096, 512 per XCD.
  int bid  = (int)blockIdx.x;
  int work = (bid & 7) * 512 + (bid >> 3);
  int mi = work >> 1;           // (b,h) flat
  int fi = work & 1;
  int bb = mi >> 7;
  int hh = mi & 127;
  int F0 = fi * 128;

  const char* bimg = (const char*)bt + (size_t)fi * 9 * 16384;
  const int boff = (wn * 4) * 2048 + lane * 16;

  bf16x8 breg[2][4][2];   // double buffer = 64 VGPR, all-static indices

  // ---- prologue: B(0) -> buf0 (issues first, flies under staging VALU) ----
  #pragma unroll
  for (int n = 0; n < 4; ++n)
    #pragma unroll
    for (int kk = 0; kk < 2; ++kk)
      breg[0][n][kk] = *(const bf16x8*)(bimg + boff + n * 2048 + kk * 1024);

  // ---- stage A rows h-1,h,h+1 -> slots 0..2 (cast in-kernel) ----
  #pragma unroll
  for (int i = 0; i < 12; ++i) {
    int idx = tid + i * 256;            // 3072 16B-blocks (3 rows)
    int cb = idx & 7;
    int w  = (idx >> 3) & 127;
    int r  = idx >> 10;                 // 0..2
    int xr = (hh + r + 127) & 127;
    const float* src = x + (((size_t)(bb * NH + xr) * NW + w) * NC + cb * 8);
    float4 a0 = *(const float4*)(src);
    float4 a1 = *(const float4*)(src + 4);
    union { unsigned short u[8]; i32x4 v; } p;
    p.u[0] = f2b(a0.x); p.u[1] = f2b(a0.y); p.u[2] = f2b(a0.z); p.u[3] = f2b(a0.w);
    p.u[4] = f2b(a1.x); p.u[5] = f2b(a1.y); p.u[6] = f2b(a1.z); p.u[7] = f2b(a1.w);
    *(i32x4*)(lds + (r * SLOT + w * 128 + ((cb ^ (w & 7)) << 4))) = p.v;
  }
  __syncthreads();    // A staged; read-only hereafter

  // compressed A-address LUT (R10-verified):
  //   addr(m,dwi) = slotb + ((trow[dwi] + m*2048) & 16383) + swz[dwi]
  //   kk=1 address = kk=0 address XOR 64
  int trow[3], swz[3];
  #pragma unroll
  for (int dwi = 0; dwi < 3; ++dwi) {
    int t = l15 + 1 - dwi;
    trow[dwi] = ((wm * 64 + t) & 127) * 128;
    swz[dwi]  = (l4 ^ (t & 7)) << 4;
  }

  f32x4 acc[4][4];   // [m][n]: swapped layout — lane holds 4 consecutive F
  #pragma unroll
  for (int m = 0; m < 4; ++m)
    #pragma unroll
    for (int n = 0; n < 4; ++n)
      acc[m][n] = (f32x4){0.f, 0.f, 0.f, 0.f};

  #pragma unroll
  for (int s = 0; s < 9; ++s) {
    if (s < 8) {  // depth-1 B prefetch -> other buffer (plain cached loads)
      const char* bs = bimg + (size_t)(s + 1) * 16384 + boff;
      #pragma unroll
      for (int n = 0; n < 4; ++n)
        #pragma unroll
        for (int kk = 0; kk < 2; ++kk)
          breg[(s + 1) & 1][n][kk] = *(const bf16x8*)(bs + n * 2048 + kk * 1024);
    }
    const int dwi   = s / 3;                  // static
    const int slotb = (2 - (s % 3)) * SLOT;   // static
    #pragma unroll
    for (int kk = 0; kk < 2; ++kk) {
      bf16x8 af[4];
      #pragma unroll
      for (int m = 0; m < 4; ++m) {
        int addr = slotb + ((trow[dwi] + m * 2048) & 16383) + swz[dwi];
        af[m] = *(const bf16x8*)(lds + (addr ^ (kk << 6)));
      }
      __builtin_amdgcn_s_setprio(1);
      #pragma unroll
      for (int m = 0; m < 4; ++m)
        #pragma unroll
        for (int n = 0; n < 4; ++n)
          acc[m][n] = __builtin_amdgcn_mfma_f32_16x16x32_bf16(
              breg[s & 1][n][kk], af[m], acc[m][n], 0, 0, 0);   // SWAPPED
      __builtin_amdgcn_s_setprio(0);
    }
  }

  // ---- epilogue: f32x4 bias + b128 LDS deposit + FULL-LINE NT stores ----
  f32x4 bq[4];
  #pragma unroll
  for (int n = 0; n < 4; ++n)
    bq[n] = *(const f32x4*)(bias + F0 + wn * 64 + n * 16 + l4 * 4);

  __syncthreads();
  float* eb = (float*)lds;              // [64][EBS=136] padded f32 tile (34.8 KB)

  #pragma unroll
  for (int chunk = 0; chunk < 2; ++chunk) {
    if (wm == chunk) {                  // owning wave-pair deposits acc+bias
      #pragma unroll
      for (int m = 0; m < 4; ++m) {
        int r = m * 16 + l15;           // 0..63 chunk-local w row
        #pragma unroll
        for (int n = 0; n < 4; ++n) {
          int c = wn * 64 + n * 16 + l4 * 4;
          *(f32x4*)(eb + r * EBS + c) = acc[m][n] + bq[n];   // one ds_write_b128
        }
      }
    }
    __syncthreads();
    size_t obase = ((size_t)mi * 128 + chunk * 64) * NF + F0;
    #pragma unroll
    for (int i = 0; i < 8; ++i) {
      int r = i * 8 + wid * 2 + (lane >> 5);
      int c = (lane & 31) * 4;
      f32x4 v = *(const f32x4*)(eb + r * EBS + c);
      __builtin_nontemporal_store(v, (f32x4*)(out + obase + (size_t)r * NF + c));
    }
    if (chunk == 0) __syncthreads();
  }
}

extern "C" void kernel_launch(void* const* d_in, const int* in_sizes, int n_in,
                              void* d_out, int out_size, void* d_ws, size_t ws_size,
                              hipStream_t stream) {
  const float* x    = (const float*)d_in[0];
  const float* kern = (const float*)d_in[1];
  const float* bias = (const float*)d_in[2];
  float* out = (float*)d_out;
  unsigned short* bt = (unsigned short*)d_ws;   // 294912 bytes

  prep_bt<<<dim3(72), dim3(256), 0, stream>>>(kern, bt);
  conv_main<<<dim3(4096), dim3(256), 0, stream>>>(x, bt, bias, out);
}

// Round 20
// 94.892 us; speedup vs baseline: 1.1896x; 1.0027x over previous
//
#include <hip/hip_runtime.h>
#include <stdint.h>
#include <stddef.h>

typedef __attribute__((ext_vector_type(8))) short bf16x8;
typedef __attribute__((ext_vector_type(4))) float f32x4;
typedef __attribute__((ext_vector_type(4))) int i32x4;

#define NH 128
#define NW 128
#define NC 64
#define NF 256
#define SLOT 16384                 // one x-row tile in LDS: [w=128][cb=8 x 16B], XOR-swizzled
#define EBS 136                    // epi row stride (floats): 544B = 34x16, aligned + uniform banks

__device__ __forceinline__ unsigned short f2b(float f) {
  union { float f; uint32_t u; } t; t.f = f;
  uint32_t u = t.u;
  return (unsigned short)((u + 0x7fffu + ((u >> 16) & 1u)) >> 16);
}

// raw barrier: orders LDS ops across waves WITHOUT draining vmcnt — in-flight
// NT stores / global loads keep flying. Correctness-verified R11/R12.
#define EPI_BAR() do { \
  asm volatile("s_waitcnt lgkmcnt(0)" ::: "memory"); \
  __builtin_amdgcn_sched_barrier(0); \
  __builtin_amdgcn_s_barrier(); \
  __builtin_amdgcn_sched_barrier(0); } while (0)

// prep: B table only (72 blocks, ~3 us). Per-wave fragment order (R8-verified):
//   u16 elem ((fi*9+s)*16 + cf*2 + kk)*512 + lane*8 + e
//     = kern[(s*64 + (kk*4+(lane>>4))*8 + e)*NF + fi*128 + cf*16 + (lane&15)]
__global__ void prep_bt(const float* __restrict__ kr, unsigned short* __restrict__ ws) {
  int t = blockIdx.x * 256 + threadIdx.x;   // [0, 18432)
  int lane = t & 63;
  int kk   = (t >> 6) & 1;
  int cf   = (t >> 7) & 7;
  int rest = t >> 10;          // fi*9 + s
  int s  = rest % 9;
  int fi = rest / 9;
  int l15 = lane & 15, l4 = lane >> 4;
  int col = fi * 128 + cf * 16 + l15;
  int k0  = s * 64 + (kk * 4 + l4) * 8;
  unsigned short* dst = ws + (size_t)t * 8;
  const float* src = kr + (size_t)k0 * NF + col;
  #pragma unroll
  for (int e = 0; e < 8; ++e) dst[e] = f2b(src[(size_t)e * NF]);
}

// conv: R19 structure (256 thr, 4 waves, 64wx64F wave tile, 3 blocks/CU,
// dbuf B, setprio, in-kernel cast, swapped MFMA operands, b128 deposit,
// FULL-LINE NT stores) with the epilogue's vmcnt-draining __syncthreads
// replaced by raw EPI_BARs: chunk0's 32KB NT-store burst drains under
// chunk1's deposit/reads and co-resident blocks instead of stalling waves.
__global__ __launch_bounds__(256, 3)
void conv_main(const float* __restrict__ x, const unsigned short* __restrict__ bt,
               const float* __restrict__ bias, float* __restrict__ out)
{
  __shared__ __align__(16) char lds[3 * SLOT];   // 48 KB (A staging; epi reuses)

  const int tid  = threadIdx.x;
  const int lane = tid & 63;
  const int l15  = lane & 15;
  const int l4   = lane >> 4;
  const int wid  = tid >> 6;
  const int wm   = wid >> 1;    // 2: w-half
  const int wn   = wid & 1;     // 2: F-half of this fi half (64 cols)

  // XCD-aware bijective swizzle: nwg=4096, 512 per XCD.
  int bid  = (int)blockIdx.x;
  int work = (bid & 7) * 512 + (bid >> 3);
  int mi = work >> 1;           // (b,h) flat
  int fi = work & 1;
  int bb = mi >> 7;
  int hh = mi & 127;
  int F0 = fi * 128;

  const char* bimg = (const char*)bt + (size_t)fi * 9 * 16384;
  const int boff = (wn * 4) * 2048 + lane * 16;

  bf16x8 breg[2][4][2];   // double buffer = 64 VGPR, all-static indices

  // ---- prologue: B(0) -> buf0 (issues first, flies under staging VALU) ----
  #pragma unroll
  for (int n = 0; n < 4; ++n)
    #pragma unroll
    for (int kk = 0; kk < 2; ++kk)
      breg[0][n][kk] = *(const bf16x8*)(bimg + boff + n * 2048 + kk * 1024);

  // ---- stage A rows h-1,h,h+1 -> slots 0..2 (cast in-kernel) ----
  #pragma unroll
  for (int i = 0; i < 12; ++i) {
    int idx = tid + i * 256;            // 3072 16B-blocks (3 rows)
    int cb = idx & 7;
    int w  = (idx >> 3) & 127;
    int r  = idx >> 10;                 // 0..2
    int xr = (hh + r + 127) & 127;
    const float* src = x + (((size_t)(bb * NH + xr) * NW + w) * NC + cb * 8);
    float4 a0 = *(const float4*)(src);
    float4 a1 = *(const float4*)(src + 4);
    union { unsigned short u[8]; i32x4 v; } p;
    p.u[0] = f2b(a0.x); p.u[1] = f2b(a0.y); p.u[2] = f2b(a0.z); p.u[3] = f2b(a0.w);
    p.u[4] = f2b(a1.x); p.u[5] = f2b(a1.y); p.u[6] = f2b(a1.z); p.u[7] = f2b(a1.w);
    *(i32x4*)(lds + (r * SLOT + w * 128 + ((cb ^ (w & 7)) << 4))) = p.v;
  }
  __syncthreads();    // A staged; read-only hereafter

  // compressed A-address LUT (R10-verified):
  //   addr(m,dwi) = slotb + ((trow[dwi] + m*2048) & 16383) + swz[dwi]
  //   kk=1 address = kk=0 address XOR 64
  int trow[3], swz[3];
  #pragma unroll
  for (int dwi = 0; dwi < 3; ++dwi) {
    int t = l15 + 1 - dwi;
    trow[dwi] = ((wm * 64 + t) & 127) * 128;
    swz[dwi]  = (l4 ^ (t & 7)) << 4;
  }

  f32x4 acc[4][4];   // [m][n]: swapped layout — lane holds 4 consecutive F
  #pragma unroll
  for (int m = 0; m < 4; ++m)
    #pragma unroll
    for (int n = 0; n < 4; ++n)
      acc[m][n] = (f32x4){0.f, 0.f, 0.f, 0.f};

  #pragma unroll
  for (int s = 0; s < 9; ++s) {
    if (s < 8) {  // depth-1 B prefetch -> other buffer (plain cached loads)
      const char* bs = bimg + (size_t)(s + 1) * 16384 + boff;
      #pragma unroll
      for (int n = 0; n < 4; ++n)
        #pragma unroll
        for (int kk = 0; kk < 2; ++kk)
          breg[(s + 1) & 1][n][kk] = *(const bf16x8*)(bs + n * 2048 + kk * 1024);
    }
    const int dwi   = s / 3;                  // static
    const int slotb = (2 - (s % 3)) * SLOT;   // static
    #pragma unroll
    for (int kk = 0; kk < 2; ++kk) {
      bf16x8 af[4];
      #pragma unroll
      for (int m = 0; m < 4; ++m) {
        int addr = slotb + ((trow[dwi] + m * 2048) & 16383) + swz[dwi];
        af[m] = *(const bf16x8*)(lds + (addr ^ (kk << 6)));
      }
      __builtin_amdgcn_s_setprio(1);
      #pragma unroll
      for (int m = 0; m < 4; ++m)
        #pragma unroll
        for (int n = 0; n < 4; ++n)
          acc[m][n] = __builtin_amdgcn_mfma_f32_16x16x32_bf16(
              breg[s & 1][n][kk], af[m], acc[m][n], 0, 0, 0);   // SWAPPED
      __builtin_amdgcn_s_setprio(0);
    }
  }

  // ---- epilogue: f32x4 bias + b128 deposit + NT full-line stores.
  //      Raw EPI_BARs only: LDS ordering without draining the NT stores. ----
  f32x4 bq[4];
  #pragma unroll
  for (int n = 0; n < 4; ++n)
    bq[n] = *(const f32x4*)(bias + F0 + wn * 64 + n * 16 + l4 * 4);

  // all LDS reads of A (lgkmcnt) must complete in every wave before eb
  // overwrites the staging slots; EPI_BAR provides exactly that.
  EPI_BAR();
  float* eb = (float*)lds;              // [64][EBS=136] padded f32 tile (34.8 KB)

  #pragma unroll
  for (int chunk = 0; chunk < 2; ++chunk) {
    if (wm == chunk) {                  // owning wave-pair deposits acc+bias
      #pragma unroll
      for (int m = 0; m < 4; ++m) {
        int r = m * 16 + l15;           // 0..63 chunk-local w row
        #pragma unroll
        for (int n = 0; n < 4; ++n) {
          int c = wn * 64 + n * 16 + l4 * 4;
          *(f32x4*)(eb + r * EBS + c) = acc[m][n] + bq[n];   // one ds_write_b128
        }
      }
    }
    EPI_BAR();                          // deposits visible (lgkmcnt only)
    size_t obase = ((size_t)mi * 128 + chunk * 64) * NF + F0;
    #pragma unroll
    for (int i = 0; i < 8; ++i) {
      int r = i * 8 + wid * 2 + (lane >> 5);
      int c = (lane & 31) * 4;
      f32x4 v = *(const f32x4*)(eb + r * EBS + c);
      __builtin_nontemporal_store(v, (f32x4*)(out + obase + (size_t)r * NF + c));
    }
    if (chunk == 0) EPI_BAR();          // eb reads done; stores keep flying
  }
}

extern "C" void kernel_launch(void* const* d_in, const int* in_sizes, int n_in,
                              void* d_out, int out_size, void* d_ws, size_t ws_size,
                              hipStream_t stream) {
  const float* x    = (const float*)d_in[0];
  const float* kern = (const float*)d_in[1];
  const float* bias = (const float*)d_in[2];
  float* out = (float*)d_out;
  unsigned short* bt = (unsigned short*)d_ws;   // 294912 bytes

  prep_bt<<<dim3(72), dim3(256), 0, stream>>>(kern, bt);
  conv_main<<<dim3(4096), dim3(256), 0, stream>>>(x, bt, bias, out);
}

// Round 21
// 91.864 us; speedup vs baseline: 1.2288x; 1.0330x over previous
//
#include <hip/hip_runtime.h>
#include <stdint.h>
#include <stddef.h>

typedef __attribute__((ext_vector_type(8))) short bf16x8;
typedef __attribute__((ext_vector_type(4))) float f32x4;
typedef __attribute__((ext_vector_type(4))) int i32x4;

#define NH 128
#define NW 128
#define NC 64
#define NF 256
#define SLOT 16384                 // one x-row tile in LDS: [w=128][cb=8 x 16B], XOR-swizzled
#define EBS 136                    // epi row stride (floats): 544B, 16B-aligned rows

__device__ __forceinline__ unsigned short f2b(float f) {
  union { float f; uint32_t u; } t; t.f = f;
  uint32_t u = t.u;
  return (unsigned short)((u + 0x7fffu + ((u >> 16) & 1u)) >> 16);
}

// raw barrier: orders LDS ops across waves WITHOUT draining vmcnt — in-flight
// NT stores keep flying. Correctness-verified R11/R12/R20.
#define EPI_BAR() do { \
  asm volatile("s_waitcnt lgkmcnt(0)" ::: "memory"); \
  __builtin_amdgcn_sched_barrier(0); \
  __builtin_amdgcn_s_barrier(); \
  __builtin_amdgcn_sched_barrier(0); } while (0)

// prep: B table only (72 blocks, ~3 us). Per-wave fragment order (R8-verified):
//   u16 elem ((fi*9+s)*16 + cf*2 + kk)*512 + lane*8 + e
//     = kern[(s*64 + (kk*4+(lane>>4))*8 + e)*NF + fi*128 + cf*16 + (lane&15)]
__global__ void prep_bt(const float* __restrict__ kr, unsigned short* __restrict__ ws) {
  int t = blockIdx.x * 256 + threadIdx.x;   // [0, 18432)
  int lane = t & 63;
  int kk   = (t >> 6) & 1;
  int cf   = (t >> 7) & 7;
  int rest = t >> 10;          // fi*9 + s
  int s  = rest % 9;
  int fi = rest / 9;
  int l15 = lane & 15, l4 = lane >> 4;
  int col = fi * 128 + cf * 16 + l15;
  int k0  = s * 64 + (kk * 4 + l4) * 8;
  unsigned short* dst = ws + (size_t)t * 8;
  const float* src = kr + (size_t)k0 * NF + col;
  #pragma unroll
  for (int e = 0; e < 8; ++e) dst[e] = f2b(src[(size_t)e * NF]);
}

// conv: R20 structure with M-TILE = 2 h-rows per block (grid 2048).
// Both rows' MFMAs consume the SAME breg inside each shift -> B L2 traffic
// halves (1.2 GB -> 0.6 GB), staging per output halves, x L2 re-reads halve.
// 4-slot LDS (rows h0-1..h0+2, 64 KB), acc[2][4][4] = 128 VGPR,
// launch_bounds(256,2) -> cap 256, 2 blocks/CU.
__global__ __launch_bounds__(256, 2)
void conv_main(const float* __restrict__ x, const unsigned short* __restrict__ bt,
               const float* __restrict__ bias, float* __restrict__ out)
{
  __shared__ __align__(16) char lds[4 * SLOT];   // 64 KB (A staging; epi reuses)

  const int tid  = threadIdx.x;
  const int lane = tid & 63;
  const int l15  = lane & 15;
  const int l4   = lane >> 4;
  const int wid  = tid >> 6;
  const int wm   = wid >> 1;    // 2: w-half
  const int wn   = wid & 1;     // 2: F-half of this fi half (64 cols)

  // XCD-aware bijective swizzle: nwg=2048, 256 per XCD.
  int bid  = (int)blockIdx.x;
  int work = (bid & 7) * 256 + (bid >> 3);
  int fi  = work & 1;
  int mi2 = work >> 1;          // 0..1023 : (b, h-pair)
  int bb  = mi2 >> 6;
  int h0  = (mi2 & 63) * 2;
  int F0  = fi * 128;

  const char* bimg = (const char*)bt + (size_t)fi * 9 * 16384;
  const int boff = (wn * 4) * 2048 + lane * 16;

  bf16x8 breg[2][4][2];   // double buffer = 64 VGPR, all-static indices

  // ---- prologue: B(0) -> buf0 (issues first, flies under staging VALU) ----
  #pragma unroll
  for (int n = 0; n < 4; ++n)
    #pragma unroll
    for (int kk = 0; kk < 2; ++kk)
      breg[0][n][kk] = *(const bf16x8*)(bimg + boff + n * 2048 + kk * 1024);

  // ---- stage A rows h0-1..h0+2 -> slots 0..3 (cast in-kernel) ----
  #pragma unroll
  for (int i = 0; i < 16; ++i) {
    int idx = tid + i * 256;            // 4096 16B-blocks (4 rows)
    int cb = idx & 7;
    int w  = (idx >> 3) & 127;
    int r  = idx >> 10;                 // 0..3
    int xr = (h0 + r + 127) & 127;      // row h0-1+r
    const float* src = x + (((size_t)(bb * NH + xr) * NW + w) * NC + cb * 8);
    float4 a0 = *(const float4*)(src);
    float4 a1 = *(const float4*)(src + 4);
    union { unsigned short u[8]; i32x4 v; } p;
    p.u[0] = f2b(a0.x); p.u[1] = f2b(a0.y); p.u[2] = f2b(a0.z); p.u[3] = f2b(a0.w);
    p.u[4] = f2b(a1.x); p.u[5] = f2b(a1.y); p.u[6] = f2b(a1.z); p.u[7] = f2b(a1.w);
    *(i32x4*)(lds + (r * SLOT + w * 128 + ((cb ^ (w & 7)) << 4))) = p.v;
  }
  __syncthreads();    // A staged; read-only hereafter

  // compressed A-address LUT (R10-verified), shared by both rows:
  //   addr(m,dwi) = slotb + ((trow[dwi] + m*2048) & 16383) + swz[dwi]
  //   kk=1 address = kk=0 address XOR 64
  int trow[3], swz[3];
  #pragma unroll
  for (int dwi = 0; dwi < 3; ++dwi) {
    int t = l15 + 1 - dwi;
    trow[dwi] = ((wm * 64 + t) & 127) * 128;
    swz[dwi]  = (l4 ^ (t & 7)) << 4;
  }

  f32x4 acc[2][4][4];   // [row][m][n], swapped layout — 128 VGPR
  #pragma unroll
  for (int rr = 0; rr < 2; ++rr)
    #pragma unroll
    for (int m = 0; m < 4; ++m)
      #pragma unroll
      for (int n = 0; n < 4; ++n)
        acc[rr][m][n] = (f32x4){0.f, 0.f, 0.f, 0.f};

  #pragma unroll
  for (int s = 0; s < 9; ++s) {
    if (s < 8) {  // depth-1 B prefetch -> other buffer (plain cached loads)
      const char* bs = bimg + (size_t)(s + 1) * 16384 + boff;
      #pragma unroll
      for (int n = 0; n < 4; ++n)
        #pragma unroll
        for (int kk = 0; kk < 2; ++kk)
          breg[(s + 1) & 1][n][kk] = *(const bf16x8*)(bs + n * 2048 + kk * 1024);
    }
    const int dwi = s / 3;                          // static
    // out row h0+rr reads x row h0+rr+1-(s%3) = slot (rr + 2 - s%3)
    #pragma unroll
    for (int kk = 0; kk < 2; ++kk) {
      #pragma unroll
      for (int rr = 0; rr < 2; ++rr) {
        const int slotb = (rr + 2 - (s % 3)) * SLOT;   // static, 0..3
        bf16x8 af[4];
        #pragma unroll
        for (int m = 0; m < 4; ++m) {
          int addr = slotb + ((trow[dwi] + m * 2048) & 16383) + swz[dwi];
          af[m] = *(const bf16x8*)(lds + (addr ^ (kk << 6)));
        }
        __builtin_amdgcn_s_setprio(1);
        #pragma unroll
        for (int m = 0; m < 4; ++m)
          #pragma unroll
          for (int n = 0; n < 4; ++n)
            acc[rr][m][n] = __builtin_amdgcn_mfma_f32_16x16x32_bf16(
                breg[s & 1][n][kk], af[m], acc[rr][m][n], 0, 0, 0);   // SWAPPED
        __builtin_amdgcn_s_setprio(0);
      }
    }
  }

  // ---- epilogue: f32x4 bias + b128 deposit + NT full-line stores,
  //      raw EPI_BARs only (R20-verified), per row x per chunk ----
  f32x4 bq[4];
  #pragma unroll
  for (int n = 0; n < 4; ++n)
    bq[n] = *(const f32x4*)(bias + F0 + wn * 64 + n * 16 + l4 * 4);

  EPI_BAR();                            // A ds_reads complete before eb overwrite
  float* eb = (float*)lds;              // [64][EBS=136] padded f32 tile (34.8 KB)

  #pragma unroll
  for (int rr = 0; rr < 2; ++rr) {
    #pragma unroll
    for (int chunk = 0; chunk < 2; ++chunk) {
      if (wm == chunk) {                // owning wave-pair deposits acc+bias
        #pragma unroll
        for (int m = 0; m < 4; ++m) {
          int r = m * 16 + l15;         // 0..63 chunk-local w row
          #pragma unroll
          for (int n = 0; n < 4; ++n) {
            int c = wn * 64 + n * 16 + l4 * 4;
            *(f32x4*)(eb + r * EBS + c) = acc[rr][m][n] + bq[n];  // ds_write_b128
          }
        }
      }
      EPI_BAR();                        // deposits visible (lgkmcnt only)
      size_t obase = ((size_t)(bb * NH + h0 + rr) * NW + chunk * 64) * NF + F0;
      #pragma unroll
      for (int i = 0; i < 8; ++i) {
        int r = i * 8 + wid * 2 + (lane >> 5);
        int c = (lane & 31) * 4;
        f32x4 v = *(const f32x4*)(eb + r * EBS + c);
        __builtin_nontemporal_store(v, (f32x4*)(out + obase + (size_t)r * NF + c));
      }
      if (rr != 1 || chunk != 1) EPI_BAR();   // eb reads done; stores keep flying
    }
  }
}

extern "C" void kernel_launch(void* const* d_in, const int* in_sizes, int n_in,
                              void* d_out, int out_size, void* d_ws, size_t ws_size,
                              hipStream_t stream) {
  const float* x    = (const float*)d_in[0];
  const float* kern = (const float*)d_in[1];
  const float* bias = (const float*)d_in[2];
  float* out = (float*)d_out;
  unsigned short* bt = (unsigned short*)d_ws;   // 294912 bytes

  prep_bt<<<dim3(72), dim3(256), 0, stream>>>(kern, bt);
  conv_main<<<dim3(2048), dim3(256), 0, stream>>>(x, bt, bias, out);
}